// Round 8
// baseline (496.387 us; speedup 1.0000x reference)
//
#include <hip/hip_runtime.h>
#include <hip/hip_fp16.h>
#include <math.h>

#define FIN 1024
#define H 512
#define DD 256
#define NCLS 4
#define MAXC 64

#define TMM 32     // rows per tile (mid mfma fallback path)
#define WCOLS 40   // mid fallback LDS pad

// ws layout (bytes), runtime C:
//   counts int[MAXC]   @ 0
//   flag   int         @ 256
//   cursor int[MAXC]   @ 512
//   offs   int[MAXC+1] @ 768
//   toff   int[MAXC+1] @ 1088
//   nzflag int         @ 1408
//   sums   double[C*H] @ 1536
//   h_ws   double[C*H]
//   ag_ws  double[C*D]
//   lists  int[n]
//   w1 hi/lo, w2 hi/lo fp16 planes; h1 fp16 frag tiles (full path)
//   xt     fp16 frag tiles of compacted x (gather tier only)
#define WS_TOFF 1088
#define WS_NZ   1408
#define WS_SUMS 1536

typedef _Float16 f16x8 __attribute__((ext_vector_type(8)));
typedef _Float16 f16x4 __attribute__((ext_vector_type(4)));
typedef _Float16 f16x2 __attribute__((ext_vector_type(2)));
typedef float    f32x4 __attribute__((ext_vector_type(4)));

// ---------------- dtype detect: int32 vs int64 cluster_id ----------------
__global__ void detect_kernel(const int* __restrict__ cid32, int* flag, int n) {
    int i = blockIdx.x * blockDim.x + threadIdx.x;
    bool p = (i < n) && (i & 1) && (cid32[i] != 0);
    unsigned long long m = __ballot(p);
    if (p && ((threadIdx.x & 63) == (__ffsll(m) - 1))) atomicOr(flag, 1);
}

__device__ __forceinline__ int get_cid(const int* cid, int flag, int i) {
    return flag ? cid[i] : cid[2 * i];   // int32, or low word of int64
}

__global__ void count_kernel(const int* __restrict__ cid, const int* __restrict__ flag,
                             int* counts, int n, int C) {
    __shared__ int lc[MAXC];
    int tid = threadIdx.x;
    if (tid < C) lc[tid] = 0;
    __syncthreads();
    int i = blockIdx.x * blockDim.x + tid;
    if (i < n) {
        int c = get_cid(cid, *flag, i);
        if ((unsigned)c < (unsigned)C) atomicAdd(&lc[c], 1);
    }
    __syncthreads();
    if (tid < C && lc[tid] > 0) atomicAdd(&counts[tid], lc[tid]);
}

__global__ void offsets_kernel(const int* __restrict__ counts, int* offs, int* toff,
                               int C, int tilesz) {
    if (threadIdx.x == 0 && blockIdx.x == 0) {
        int s = 0, ts = 0;
        offs[0] = 0; toff[0] = 0;
        for (int c = 0; c < C; c++) {
            s += counts[c];                          offs[c + 1] = s;
            ts += (counts[c] + tilesz - 1) / tilesz; toff[c + 1] = ts;
        }
    }
}

__global__ void compact_kernel(const int* __restrict__ cid, const int* __restrict__ flag,
                               const int* __restrict__ offs, int* cursor,
                               int* lists, int n, int C) {
    __shared__ int lc[MAXC], lbase[MAXC], lpos[MAXC];
    int tid = threadIdx.x;
    if (tid < C) { lc[tid] = 0; lpos[tid] = 0; }
    __syncthreads();
    int i = blockIdx.x * blockDim.x + tid;
    int c = -1;
    if (i < n) {
        int cc = get_cid(cid, *flag, i);
        if ((unsigned)cc < (unsigned)C) { c = cc; atomicAdd(&lc[c], 1); }
    }
    __syncthreads();
    if (tid < C && lc[tid] > 0) lbase[tid] = atomicAdd(&cursor[tid], lc[tid]);
    __syncthreads();
    if (c >= 0) {
        int p = atomicAdd(&lpos[c], 1);
        lists[offs[c] + lbase[c] + p] = i;
    }
}

// ================= full path: frag-swizzled layouts + global_load_lds =======

// 16B-granule XOR swizzle: bijective within each 8KB (128 x 32 f16) tile.
__device__ __forceinline__ int frag_off(int r, int g) {
    int blk = r >> 1;
    int slot = (((r & 1) << 2) | g) ^ (blk & 7);
    return blk * 128 + slot * 16;
}

// one wave moves 1KB: per-lane 16B from g(+lane*16 applied) to lds base
__device__ __forceinline__ void gload1k(const char* g, char* l) {
    __builtin_amdgcn_global_load_lds(
        (const __attribute__((address_space(1))) void*)g,
        (__attribute__((address_space(3))) void*)l, 16, 0, 0);
}

// ---- weight prep: W[c][K][N(=512)] fp32 -> hi/lo fp16 frag-swizzled tiles --
__device__ __forceinline__ void wprep_body(
    const float* __restrict__ W, _Float16* __restrict__ hi,
    _Float16* __restrict__ lo, int K, int b, float sw[32][132], int tid)
{
    int ktn = K >> 5;
    int c = b / (4 * ktn);
    int rem = b % (4 * ktn);
    int nb = rem / ktn, kt = rem % ktn;
    const float* Wc = W + (size_t)c * K * H + (size_t)(kt * 32) * H + nb * 128;
#pragma unroll
    for (int it = 0; it < 4; it++) {
        int id = it * 256 + tid;
        int r = id >> 5, c4 = (id & 31) * 4;
        *(float4*)&sw[r][c4] = *(const float4*)(Wc + (size_t)r * H + c4);
    }
    __syncthreads();
    size_t tile = ((size_t)(c * 4 + nb)) * ktn + kt;
    char* hp = (char*)hi + tile * 8192;
    char* lp = (char*)lo + tile * 8192;
#pragma unroll
    for (int it = 0; it < 2; it++) {
        int fi = it * 256 + tid;          // frag 0..511
        int cl = fi >> 2, g = fi & 3;
        f16x8 hv, lv;
#pragma unroll
        for (int e = 0; e < 8; e++) {
            float v = sw[g * 8 + e][cl];
            _Float16 h = (_Float16)v;
            hv[e] = h;
            lv[e] = (_Float16)(v - (float)h);
        }
        int off = frag_off(cl, g);
        *(f16x8*)(hp + off) = hv;
        *(f16x8*)(lp + off) = lv;
    }
}

// ---- x prep: gather row lists[.], fp32->fp16, write frag-tiled xt ----------
// xt layout = h1 layout: tile t has 32 k-slices x 8KB, slice = 128rows x 32k.
__device__ __forceinline__ void xtprep_body(
    const float* __restrict__ x, _Float16* __restrict__ xt,
    const int* __restrict__ counts, const int* __restrict__ offs,
    const int* __restrict__ toff, const int* __restrict__ lists,
    int C, int b2, int tid)
{
    int t = b2 >> 3, kg = b2 & 7;        // kg: 128-k chunk (4 slices)
    int c = 0;
    while (c + 1 < C && t >= toff[c + 1]) c++;
    int cnt = counts[c];
    int row0 = (t - toff[c]) * 128;
    int r = tid & 127;
    int ktl0 = tid >> 7;                 // 0 or 1; +2 on second pass
    int rg = row0 + r;
    int gi = (t < toff[C] && rg < cnt) ? lists[offs[c] + rg] : -1;
    const float* src = x + (size_t)(gi < 0 ? 0 : gi) * FIN + kg * 128;
    char* dst = (char*)xt + ((size_t)t * 32 + kg * 4) * 8192;
#pragma unroll
    for (int q = 0; q < 2; q++) {
        int ktl = ktl0 + q * 2;
        f16x8 gr[4];
        if (gi >= 0) {
#pragma unroll
            for (int g4 = 0; g4 < 4; g4++) {
                float4 a = *(const float4*)(src + ktl * 32 + g4 * 8);
                float4 b = *(const float4*)(src + ktl * 32 + g4 * 8 + 4);
                gr[g4] = (f16x8){ (_Float16)a.x, (_Float16)a.y, (_Float16)a.z, (_Float16)a.w,
                                  (_Float16)b.x, (_Float16)b.y, (_Float16)b.z, (_Float16)b.w };
            }
        } else {
#pragma unroll
            for (int g4 = 0; g4 < 4; g4++) gr[g4] = (f16x8){0,0,0,0,0,0,0,0};
        }
        char* d = dst + (size_t)ktl * 8192;
#pragma unroll
        for (int g4 = 0; g4 < 4; g4++)
            *(f16x8*)(d + frag_off(r, g4)) = gr[g4];
    }
}

// merged BW-bound prep: weight split (both layers) + xt build, one launch
__global__ __launch_bounds__(256) void prep_all(
    const float* __restrict__ W1, _Float16* __restrict__ w1h, _Float16* __restrict__ w1l,
    const float* __restrict__ W2, _Float16* __restrict__ w2h, _Float16* __restrict__ w2l,
    const float* __restrict__ x, _Float16* __restrict__ xt,
    const int* __restrict__ counts, const int* __restrict__ offs,
    const int* __restrict__ toff, const int* __restrict__ lists, int C)
{
    __shared__ float sw[32][132];
    int nW1 = C * 4 * (FIN / 32);
    int nW2 = C * 4 * (H / 32);
    int b = blockIdx.x, tid = threadIdx.x;
    if (b < nW1)            wprep_body(W1, w1h, w1l, FIN, b, sw, tid);
    else if (b < nW1 + nW2) wprep_body(W2, w2h, w2l, H, b - nW1, sw, tid);
    else                    xtprep_body(x, xt, counts, offs, toff, lists, C,
                                        b - nW1 - nW2, tid);
}

// standalone weight prep (ws_full tier without xt)
__global__ __launch_bounds__(256) void wprep_both(
    const float* __restrict__ W1, _Float16* __restrict__ w1h, _Float16* __restrict__ w1l,
    const float* __restrict__ W2, _Float16* __restrict__ w2h, _Float16* __restrict__ w2l,
    int C)
{
    __shared__ float sw[32][132];
    int n1 = C * 4 * (FIN / 32);
    int b = blockIdx.x;
    int tid = threadIdx.x;
    if (b < n1) wprep_body(W1, w1h, w1l, FIN, b, sw, tid);
    else        wprep_body(W2, w2h, w2l, H, b - n1, sw, tid);
}

// ---- layer1 GEMM (xt tier): ALL staging linear global_load_lds, BK=64 ------
// m97 2-barrier single-buffer loop, x2 K-unroll: 64 MFMAs per barrier pair.
// A comes pre-gathered/pre-tiled from xt -> structure identical to gemm2.
struct __align__(16) G1Smem {
    union {
        struct { _Float16 A[2][4096]; _Float16 Bh[2][4096]; _Float16 Bl[2][4096]; } s; // 48KB
        _Float16 Ct[128][132];                                                          // 33.8KB
    } u;
};

__global__ __launch_bounds__(256, 3) void gemm1(
    const _Float16* __restrict__ xt,
    const int* __restrict__ toff,
    const _Float16* __restrict__ wh, const _Float16* __restrict__ wl,
    const float* __restrict__ b1, _Float16* __restrict__ h1,
    int C, int nwg)
{
    int bid = blockIdx.x;
    {   // bijective XCD swizzle (m204)
        int q = nwg >> 3, r = nwg & 7, xcd = bid & 7, k = bid >> 3;
        bid = (xcd < r ? xcd * (q + 1) : r * (q + 1) + (xcd - r) * q) + k;
    }
    int ntile = toff[C];
    if (bid >= ntile * 4) return;
    int t = bid >> 2, nb = bid & 3;
    int c = 0;
    while (c + 1 < C && t >= toff[c + 1]) c++;

    __shared__ G1Smem sm;
    int tid = threadIdx.x;
    int lane = tid & 63;
    int wave = __builtin_amdgcn_readfirstlane(tid >> 6);
    int ch = wave * 2;
    int wr = wave >> 1, wq = wave & 1;
    int l15 = lane & 15, g = lane >> 4;

    const char* gA = (const char*)xt + (size_t)t * 32 * 8192;
    const char* gh = (const char*)wh + ((size_t)(c * 4 + nb) * 32) * 8192;
    const char* gl = (const char*)wl + ((size_t)(c * 4 + nb) * 32) * 8192;
    char* ldsA  = (char*)sm.u.s.A;
    char* ldsBh = (char*)sm.u.s.Bh;
    char* ldsBl = (char*)sm.u.s.Bl;

    f32x4 acc[4][4];
#pragma unroll
    for (int i = 0; i < 4; i++)
#pragma unroll
        for (int j = 0; j < 4; j++) acc[i][j] = (f32x4){0.f, 0.f, 0.f, 0.f};

    for (int kt2 = 0; kt2 < 16; kt2++) {
        __syncthreads();   // prev compute done: LDS reusable
        {
            const char* ga  = gA + (size_t)(kt2 * 2) * 8192 + ch * 1024 + lane * 16;
            const char* gsh = gh + (size_t)(kt2 * 2) * 8192 + ch * 1024 + lane * 16;
            const char* gsl = gl + (size_t)(kt2 * 2) * 8192 + ch * 1024 + lane * 16;
#pragma unroll
            for (int s = 0; s < 2; s++) {
                gload1k(ga  + s * 8192,        ldsA  + s * 8192 + ch * 1024);
                gload1k(ga  + s * 8192 + 1024, ldsA  + s * 8192 + ch * 1024 + 1024);
                gload1k(gsh + s * 8192,        ldsBh + s * 8192 + ch * 1024);
                gload1k(gsh + s * 8192 + 1024, ldsBh + s * 8192 + ch * 1024 + 1024);
                gload1k(gsl + s * 8192,        ldsBl + s * 8192 + ch * 1024);
                gload1k(gsl + s * 8192 + 1024, ldsBl + s * 8192 + ch * 1024 + 1024);
            }
        }
        __syncthreads();   // drain: LDS populated
#pragma unroll
        for (int s = 0; s < 2; s++) {
            f16x8 a[4], bh[4], bl[4];
#pragma unroll
            for (int fr = 0; fr < 4; fr++)
                a[fr] = *(const f16x8*)(ldsA + s * 8192 + frag_off(wr * 64 + fr * 16 + l15, g));
#pragma unroll
            for (int fc = 0; fc < 4; fc++) {
                int col = wq * 64 + fc * 16 + l15;
                bh[fc] = *(const f16x8*)(ldsBh + s * 8192 + frag_off(col, g));
                bl[fc] = *(const f16x8*)(ldsBl + s * 8192 + frag_off(col, g));
            }
#pragma unroll
            for (int fr = 0; fr < 4; fr++)
#pragma unroll
                for (int fc = 0; fc < 4; fc++) {
                    acc[fr][fc] = __builtin_amdgcn_mfma_f32_16x16x32_f16(a[fr], bh[fc], acc[fr][fc], 0, 0, 0);
                    acc[fr][fc] = __builtin_amdgcn_mfma_f32_16x16x32_f16(a[fr], bl[fc], acc[fr][fc], 0, 0, 0);
                }
        }
    }
    __syncthreads();   // staging LDS dead before union reuse
    const float* b1c = b1 + (size_t)c * H + nb * 128;
#pragma unroll
    for (int fc = 0; fc < 4; fc++) {
        int colL = wq * 64 + fc * 16 + l15;
        float bv = b1c[colL];
#pragma unroll
        for (int fr = 0; fr < 4; fr++)
#pragma unroll
            for (int j = 0; j < 4; j++) {
                int rowL = wr * 64 + fr * 16 + g * 4 + j;
                float v = acc[fr][fc][j] + bv;
                sm.u.Ct[rowL][colL] = (_Float16)(v > 0.f ? v : 0.f);
            }
    }
    __syncthreads();
    char* hout = (char*)h1 + ((size_t)t * 16 + nb * 4) * 8192;
#pragma unroll
    for (int ktl = 0; ktl < 4; ktl++)
#pragma unroll
        for (int it = 0; it < 2; it++) {
            int fi = it * 256 + tid;
            int rl = fi >> 2, gg = fi & 3;
            f16x8 v = *(const f16x8*)&sm.u.Ct[rl][ktl * 32 + gg * 8];
            *(f16x8*)(hout + (size_t)ktl * 8192 + frag_off(rl, gg)) = v;
        }
}

// ---- layer1 GEMM (reg-gather tier, round-5 proven; used when no xt ws) -----
struct __align__(16) GSmem {
    union {
        struct { _Float16 A[2][4096]; _Float16 Bh[2][4096]; _Float16 Bl[2][4096]; } s;
        _Float16 Ct[128][132];
    } u;
    int sIdx[128];
};

__global__ __launch_bounds__(256, 3) void gemm1_reg(
    const float* __restrict__ x,
    const int* __restrict__ counts, const int* __restrict__ offs,
    const int* __restrict__ toff, const int* __restrict__ lists,
    const _Float16* __restrict__ wh, const _Float16* __restrict__ wl,
    const float* __restrict__ b1, _Float16* __restrict__ h1,
    int C, int nwg)
{
    int bid = blockIdx.x;
    {
        int q = nwg >> 3, r = nwg & 7, xcd = bid & 7, k = bid >> 3;
        bid = (xcd < r ? xcd * (q + 1) : r * (q + 1) + (xcd - r) * q) + k;
    }
    int ntile = toff[C];
    if (bid >= ntile * 4) return;
    int t = bid >> 2, nb = bid & 3;
    int c = 0;
    while (c + 1 < C && t >= toff[c + 1]) c++;
    int cnt = counts[c];
    int row0 = (t - toff[c]) * 128;

    __shared__ GSmem sm;
    int tid = threadIdx.x;
    int lane = tid & 63;
    int wave = __builtin_amdgcn_readfirstlane(tid >> 6);
    if (tid < 128) {
        int r = row0 + tid;
        sm.sIdx[tid] = (r < cnt) ? lists[offs[c] + r] : -1;
    }
    __syncthreads();

    int r0 = tid >> 2, g0 = tid & 3;
    int gi0 = sm.sIdx[r0], gi1 = sm.sIdx[64 + r0];
    const float* xp0 = x + (size_t)(gi0 < 0 ? 0 : gi0) * FIN + g0 * 8;
    const float* xp1 = x + (size_t)(gi1 < 0 ? 0 : gi1) * FIN + g0 * 8;
    int aoff0 = frag_off(r0, g0), aoff1 = frag_off(64 + r0, g0);

    const char* gh = (const char*)wh + ((size_t)(c * 4 + nb) * 32) * 8192;
    const char* gl = (const char*)wl + ((size_t)(c * 4 + nb) * 32) * 8192;
    char* ldsA  = (char*)sm.u.s.A;
    char* ldsBh = (char*)sm.u.s.Bh;
    char* ldsBl = (char*)sm.u.s.Bl;
    int ch = wave * 2;

    int wr = wave >> 1, wq = wave & 1;
    int l15 = lane & 15, g = lane >> 4;

    f32x4 acc[4][4];
#pragma unroll
    for (int i = 0; i < 4; i++)
#pragma unroll
        for (int j = 0; j < 4; j++) acc[i][j] = (f32x4){0.f, 0.f, 0.f, 0.f};

    {
        const char* gsh = gh + ch * 1024 + lane * 16;
        const char* gsl = gl + ch * 1024 + lane * 16;
        gload1k(gsh,        ldsBh + ch * 1024);
        gload1k(gsh + 1024, ldsBh + ch * 1024 + 1024);
        gload1k(gsl,        ldsBl + ch * 1024);
        gload1k(gsl + 1024, ldsBl + ch * 1024 + 1024);
        float4 v0a = make_float4(0.f,0.f,0.f,0.f), v0b = v0a, v1a = v0a, v1b = v0a;
        if (gi0 >= 0) { v0a = *(const float4*)xp0; v0b = *(const float4*)(xp0 + 4); }
        if (gi1 >= 0) { v1a = *(const float4*)xp1; v1b = *(const float4*)(xp1 + 4); }
        f16x8 a0 = { (_Float16)v0a.x, (_Float16)v0a.y, (_Float16)v0a.z, (_Float16)v0a.w,
                     (_Float16)v0b.x, (_Float16)v0b.y, (_Float16)v0b.z, (_Float16)v0b.w };
        f16x8 a1 = { (_Float16)v1a.x, (_Float16)v1a.y, (_Float16)v1a.z, (_Float16)v1a.w,
                     (_Float16)v1b.x, (_Float16)v1b.y, (_Float16)v1b.z, (_Float16)v1b.w };
        *(f16x8*)(ldsA + aoff0) = a0;
        *(f16x8*)(ldsA + aoff1) = a1;
        xp0 += 32; xp1 += 32;
    }
    __syncthreads();

    int cur = 0;
    for (int kt = 0; kt < 32; kt++) {
        int nxt = cur ^ 1;
        bool pf = kt < 31;
        float4 v0a = make_float4(0.f,0.f,0.f,0.f), v0b = v0a, v1a = v0a, v1b = v0a;
        if (pf) {
            const char* gsh = gh + (size_t)(kt + 1) * 8192 + ch * 1024 + lane * 16;
            const char* gsl = gl + (size_t)(kt + 1) * 8192 + ch * 1024 + lane * 16;
            gload1k(gsh,        ldsBh + nxt * 8192 + ch * 1024);
            gload1k(gsh + 1024, ldsBh + nxt * 8192 + ch * 1024 + 1024);
            gload1k(gsl,        ldsBl + nxt * 8192 + ch * 1024);
            gload1k(gsl + 1024, ldsBl + nxt * 8192 + ch * 1024 + 1024);
            if (gi0 >= 0) { v0a = *(const float4*)xp0; v0b = *(const float4*)(xp0 + 4); }
            if (gi1 >= 0) { v1a = *(const float4*)xp1; v1b = *(const float4*)(xp1 + 4); }
            xp0 += 32; xp1 += 32;
        }
        f16x8 a[4], bh[4], bl[4];
#pragma unroll
        for (int fr = 0; fr < 4; fr++)
            a[fr] = *(const f16x8*)(ldsA + cur * 8192 + frag_off(wr * 64 + fr * 16 + l15, g));
#pragma unroll
        for (int fc = 0; fc < 4; fc++) {
            int col = wq * 64 + fc * 16 + l15;
            bh[fc] = *(const f16x8*)(ldsBh + cur * 8192 + frag_off(col, g));
            bl[fc] = *(const f16x8*)(ldsBl + cur * 8192 + frag_off(col, g));
        }
#pragma unroll
        for (int fr = 0; fr < 4; fr++)
#pragma unroll
            for (int fc = 0; fc < 4; fc++) {
                acc[fr][fc] = __builtin_amdgcn_mfma_f32_16x16x32_f16(a[fr], bh[fc], acc[fr][fc], 0, 0, 0);
                acc[fr][fc] = __builtin_amdgcn_mfma_f32_16x16x32_f16(a[fr], bl[fc], acc[fr][fc], 0, 0, 0);
            }
        if (pf) {
            f16x8 a0 = { (_Float16)v0a.x, (_Float16)v0a.y, (_Float16)v0a.z, (_Float16)v0a.w,
                         (_Float16)v0b.x, (_Float16)v0b.y, (_Float16)v0b.z, (_Float16)v0b.w };
            f16x8 a1 = { (_Float16)v1a.x, (_Float16)v1a.y, (_Float16)v1a.z, (_Float16)v1a.w,
                         (_Float16)v1b.x, (_Float16)v1b.y, (_Float16)v1b.z, (_Float16)v1b.w };
            *(f16x8*)(ldsA + nxt * 8192 + aoff0) = a0;
            *(f16x8*)(ldsA + nxt * 8192 + aoff1) = a1;
        }
        __syncthreads();
        cur = nxt;
    }
    __syncthreads();
    const float* b1c = b1 + (size_t)c * H + nb * 128;
#pragma unroll
    for (int fc = 0; fc < 4; fc++) {
        int colL = wq * 64 + fc * 16 + l15;
        float bv = b1c[colL];
#pragma unroll
        for (int fr = 0; fr < 4; fr++)
#pragma unroll
            for (int j = 0; j < 4; j++) {
                int rowL = wr * 64 + fr * 16 + g * 4 + j;
                float v = acc[fr][fc][j] + bv;
                sm.u.Ct[rowL][colL] = (_Float16)(v > 0.f ? v : 0.f);
            }
    }
    __syncthreads();
    char* hout = (char*)h1 + ((size_t)t * 16 + nb * 4) * 8192;
#pragma unroll
    for (int ktl = 0; ktl < 4; ktl++)
#pragma unroll
        for (int it = 0; it < 2; it++) {
            int fi = it * 256 + tid;
            int rl = fi >> 2, gg = fi & 3;
            f16x8 v = *(const f16x8*)&sm.u.Ct[rl][ktl * 32 + gg * 8];
            *(f16x8*)(hout + (size_t)ktl * 8192 + frag_off(rl, gg)) = v;
        }
}

// ---- layer2 GEMM: m97-style single-buffer BK=64, all-gload_lds -------------
__global__ __launch_bounds__(256, 3) void gemm2(
    const _Float16* __restrict__ h1,
    const int* __restrict__ counts, const int* __restrict__ toff,
    const _Float16* __restrict__ wh, const _Float16* __restrict__ wl,
    const float* __restrict__ b2, double* __restrict__ sums,
    int C, int nwg)
{
    int bid = blockIdx.x;
    {
        int q = nwg >> 3, r = nwg & 7, xcd = bid & 7, k = bid >> 3;
        bid = (xcd < r ? xcd * (q + 1) : r * (q + 1) + (xcd - r) * q) + k;
    }
    int ntile = toff[C];
    if (bid >= ntile * 4) return;
    int t = bid >> 2, nb = bid & 3;
    int c = 0;
    while (c + 1 < C && t >= toff[c + 1]) c++;
    int cnt = counts[c];
    int row0 = (t - toff[c]) * 128;

    __shared__ alignas(16) _Float16 sA2[2][4096];   // two 32-k sub-tiles
    __shared__ alignas(16) _Float16 sBh2[2][4096];
    __shared__ alignas(16) _Float16 sBl2[2][4096];

    int tid = threadIdx.x;
    int lane = tid & 63;
    int wave = __builtin_amdgcn_readfirstlane(tid >> 6);
    int wr = wave >> 1, wq = wave & 1;
    int l15 = lane & 15, g = lane >> 4;
    int ch = wave * 2;

    const char* gA = (const char*)h1 + (size_t)t * 16 * 8192;
    const char* gh = (const char*)wh + ((size_t)(c * 4 + nb) * 16) * 8192;
    const char* gl = (const char*)wl + ((size_t)(c * 4 + nb) * 16) * 8192;

    f32x4 acc[4][4];
#pragma unroll
    for (int i = 0; i < 4; i++)
#pragma unroll
        for (int j = 0; j < 4; j++) acc[i][j] = (f32x4){0.f, 0.f, 0.f, 0.f};

    for (int kt2 = 0; kt2 < 8; kt2++) {
        __syncthreads();   // prev compute done
        {
            const char* ga  = gA + (size_t)(kt2 * 2) * 8192 + ch * 1024 + lane * 16;
            const char* gsh = gh + (size_t)(kt2 * 2) * 8192 + ch * 1024 + lane * 16;
            const char* gsl = gl + (size_t)(kt2 * 2) * 8192 + ch * 1024 + lane * 16;
#pragma unroll
            for (int s = 0; s < 2; s++) {
                gload1k(ga  + s * 8192,        (char*)sA2  + s * 8192 + ch * 1024);
                gload1k(ga  + s * 8192 + 1024, (char*)sA2  + s * 8192 + ch * 1024 + 1024);
                gload1k(gsh + s * 8192,        (char*)sBh2 + s * 8192 + ch * 1024);
                gload1k(gsh + s * 8192 + 1024, (char*)sBh2 + s * 8192 + ch * 1024 + 1024);
                gload1k(gsl + s * 8192,        (char*)sBl2 + s * 8192 + ch * 1024);
                gload1k(gsl + s * 8192 + 1024, (char*)sBl2 + s * 8192 + ch * 1024 + 1024);
            }
        }
        __syncthreads();   // drain
#pragma unroll
        for (int s = 0; s < 2; s++) {
            f16x8 a[4], bh[4], bl[4];
#pragma unroll
            for (int fr = 0; fr < 4; fr++)
                a[fr] = *(const f16x8*)((char*)sA2 + s * 8192 + frag_off(wr * 64 + fr * 16 + l15, g));
#pragma unroll
            for (int fc = 0; fc < 4; fc++) {
                int col = wq * 64 + fc * 16 + l15;
                bh[fc] = *(const f16x8*)((char*)sBh2 + s * 8192 + frag_off(col, g));
                bl[fc] = *(const f16x8*)((char*)sBl2 + s * 8192 + frag_off(col, g));
            }
#pragma unroll
            for (int fr = 0; fr < 4; fr++)
#pragma unroll
                for (int fc = 0; fc < 4; fc++) {
                    acc[fr][fc] = __builtin_amdgcn_mfma_f32_16x16x32_f16(a[fr], bh[fc], acc[fr][fc], 0, 0, 0);
                    acc[fr][fc] = __builtin_amdgcn_mfma_f32_16x16x32_f16(a[fr], bl[fc], acc[fr][fc], 0, 0, 0);
                }
        }
    }
    // epilogue: bias+relu, row-validity mask, column sums -> double atomics
    const float* b2c = b2 + (size_t)c * H + nb * 128;
    int rbound = cnt - row0;
    float psum[4];
#pragma unroll
    for (int fc = 0; fc < 4; fc++) {
        int colL = wq * 64 + fc * 16 + l15;
        float bv = b2c[colL];
        float s = 0.f;
#pragma unroll
        for (int fr = 0; fr < 4; fr++)
#pragma unroll
            for (int j = 0; j < 4; j++) {
                int rowL = wr * 64 + fr * 16 + g * 4 + j;
                float v = acc[fr][fc][j] + bv;
                v = v > 0.f ? v : 0.f;
                if (rowL < rbound) s += v;
            }
        psum[fc] = s;
    }
#pragma unroll
    for (int fc = 0; fc < 4; fc++) {
        psum[fc] += __shfl_xor(psum[fc], 16);
        psum[fc] += __shfl_xor(psum[fc], 32);
    }
    if (g == 0) {
#pragma unroll
        for (int fc = 0; fc < 4; fc++)
            atomicAdd(&sums[(size_t)c * H + nb * 128 + wq * 64 + fc * 16 + l15],
                      (double)psum[fc]);
    }
}

// ================= mid fallback (round-1 proven mfma path) ==================
__global__ __launch_bounds__(256) void wsplit_kernel(
    const float* __restrict__ W, _Float16* __restrict__ hi,
    _Float16* __restrict__ lo, int K, int N)
{
    __shared__ float tile[64][65];
    int tid = threadIdx.x;
    int tilesN = N >> 6, tilesK = K >> 6;
    int b = blockIdx.x;
    int c = b / (tilesK * tilesN);
    int r = b % (tilesK * tilesN);
    int tk = r / tilesN, tn = r % tilesN;
    const float* Wc = W + (size_t)c * K * N;
    int k0 = tk << 6, n0 = tn << 6;
#pragma unroll
    for (int it = 0; it < 16; it++) {
        int id = it * 256 + tid;
        int kr = id >> 6, nc = id & 63;
        tile[kr][nc] = Wc[(size_t)(k0 + kr) * N + n0 + nc];
    }
    __syncthreads();
    _Float16* hic = hi + (size_t)c * N * K;
    _Float16* loc = lo + (size_t)c * N * K;
#pragma unroll
    for (int it = 0; it < 8; it++) {
        int id = it * 256 + tid;
        int nc = id >> 5, kp = (id & 31) * 2;
        float a0 = tile[kp][nc], a1 = tile[kp + 1][nc];
        _Float16 h0 = (_Float16)a0, h1v = (_Float16)a1;
        _Float16 l0 = (_Float16)(a0 - (float)h0);
        _Float16 l1 = (_Float16)(a1 - (float)h1v);
        size_t off = (size_t)(n0 + nc) * K + k0 + kp;
        f16x2 hv = {h0, h1v}, lv = {l0, l1};
        *(f16x2*)(hic + off) = hv;
        *(f16x2*)(loc + off) = lv;
    }
}

struct __align__(16) MfmaSmem {
    _Float16 sW[2][128][WCOLS];
    _Float16 sH[TMM][520];
    _Float16 sX[TMM][WCOLS];
    int      sIdx[TMM];
};

__global__ __launch_bounds__(256, 2) void mlp_mfma(
    const float* __restrict__ x,
    const int* __restrict__ counts, const int* __restrict__ offs,
    const int* __restrict__ toff, const int* __restrict__ lists,
    const _Float16* __restrict__ w1h, const _Float16* __restrict__ w1l,
    const _Float16* __restrict__ w2h, const _Float16* __restrict__ w2l,
    const float* __restrict__ b1, const float* __restrict__ b2,
    double* __restrict__ sums, int C, int nwg)
{
    int bid = blockIdx.x;
    {
        int q = nwg >> 3, r = nwg & 7, xcd = bid & 7, k = bid >> 3;
        bid = (xcd < r ? xcd * (q + 1) : r * (q + 1) + (xcd - r) * q) + k;
    }
    if (bid >= toff[C]) return;
    int c = 0;
    while (c + 1 < C && bid >= toff[c + 1]) c++;
    int t = bid - toff[c];
    int cnt = counts[c];
    int row0 = t * TMM;

    __shared__ MfmaSmem sm;
    int tid  = threadIdx.x;
    int lane = tid & 63, wave = tid >> 6;
    int wr = wave >> 1, wq = wave & 1;
    int l15 = lane & 15, g = lane >> 4;

    if (tid < TMM) {
        int r = row0 + tid;
        sm.sIdx[tid] = (r < cnt) ? lists[offs[c] + r] : -1;
    }

    const _Float16* w1hc = w1h + (size_t)c * FIN * H;
    const _Float16* w1lc = w1l + (size_t)c * FIN * H;
    const _Float16* w2hc = w2h + (size_t)c * H * H;
    const _Float16* w2lc = w2l + (size_t)c * H * H;
    const float* b1c = b1 + (size_t)c * H;
    const float* b2c = b2 + (size_t)c * H;

    int xr = tid >> 3;
    int xk = (tid & 7) * 4;
    int s_lc = tid >> 2;
    int s_kc = (tid & 3) * 8;

    for (int nb = 0; nb < H; nb += 128) {
        f32x4 acc[4];
#pragma unroll
        for (int f = 0; f < 4; f++) acc[f] = (f32x4){0.f, 0.f, 0.f, 0.f};

        for (int kk = 0; kk < FIN; kk += 32) {
            __syncthreads();
            {
                int gi = sm.sIdx[xr];
                float4 v = make_float4(0.f, 0.f, 0.f, 0.f);
                if (gi >= 0) v = *(const float4*)(x + (size_t)gi * FIN + kk + xk);
                f16x4 hv = { (_Float16)v.x, (_Float16)v.y, (_Float16)v.z, (_Float16)v.w };
                *(f16x4*)&sm.sX[xr][xk] = hv;
            }
            {
                const _Float16* ph = w1hc + (size_t)(nb + s_lc) * FIN + kk + s_kc;
                const _Float16* pl = w1lc + (size_t)(nb + s_lc) * FIN + kk + s_kc;
                *(f16x8*)&sm.sW[0][s_lc][s_kc]      = *(const f16x8*)ph;
                *(f16x8*)&sm.sW[0][64 + s_lc][s_kc] = *(const f16x8*)(ph + (size_t)64 * FIN);
                *(f16x8*)&sm.sW[1][s_lc][s_kc]      = *(const f16x8*)pl;
                *(f16x8*)&sm.sW[1][64 + s_lc][s_kc] = *(const f16x8*)(pl + (size_t)64 * FIN);
            }
            __syncthreads();
            f16x8 a = *(const f16x8*)&sm.sX[wr * 16 + l15][g * 8];
#pragma unroll
            for (int f = 0; f < 4; f++) {
                int lc = wq * 64 + f * 16 + l15;
                f16x8 bh = *(const f16x8*)&sm.sW[0][lc][g * 8];
                f16x8 bl = *(const f16x8*)&sm.sW[1][lc][g * 8];
                acc[f] = __builtin_amdgcn_mfma_f32_16x16x32_f16(a, bh, acc[f], 0, 0, 0);
                acc[f] = __builtin_amdgcn_mfma_f32_16x16x32_f16(a, bl, acc[f], 0, 0, 0);
            }
        }
#pragma unroll
        for (int f = 0; f < 4; f++) {
            int col = nb + wq * 64 + f * 16 + l15;
            float bv = b1c[col];
#pragma unroll
            for (int j = 0; j < 4; j++) {
                int row = wr * 16 + g * 4 + j;
                float v = acc[f][j] + bv;
                sm.sH[row][col] = (_Float16)(v > 0.f ? v : 0.f);
            }
        }
    }

    for (int nb = 0; nb < H; nb += 128) {
        f32x4 acc[4];
#pragma unroll
        for (int f = 0; f < 4; f++) acc[f] = (f32x4){0.f, 0.f, 0.f, 0.f};

        for (int kk = 0; kk < H; kk += 32) {
            __syncthreads();
            {
                const _Float16* ph = w2hc + (size_t)(nb + s_lc) * H + kk + s_kc;
                const _Float16* pl = w2lc + (size_t)(nb + s_lc) * H + kk + s_kc;
                *(f16x8*)&sm.sW[0][s_lc][s_kc]      = *(const f16x8*)ph;
                *(f16x8*)&sm.sW[0][64 + s_lc][s_kc] = *(const f16x8*)(ph + (size_t)64 * H);
                *(f16x8*)&sm.sW[1][s_lc][s_kc]      = *(const f16x8*)pl;
                *(f16x8*)&sm.sW[1][64 + s_lc][s_kc] = *(const f16x8*)(pl + (size_t)64 * H);
            }
            __syncthreads();
            f16x8 a = *(const f16x8*)&sm.sH[wr * 16 + l15][kk + g * 8];
#pragma unroll
            for (int f = 0; f < 4; f++) {
                int lc = wq * 64 + f * 16 + l15;
                f16x8 bh = *(const f16x8*)&sm.sW[0][lc][g * 8];
                f16x8 bl = *(const f16x8*)&sm.sW[1][lc][g * 8];
                acc[f] = __builtin_amdgcn_mfma_f32_16x16x32_f16(a, bh, acc[f], 0, 0, 0);
                acc[f] = __builtin_amdgcn_mfma_f32_16x16x32_f16(a, bl, acc[f], 0, 0, 0);
            }
        }
        float psum[4];
#pragma unroll
        for (int f = 0; f < 4; f++) {
            int col = nb + wq * 64 + f * 16 + l15;
            float bv = b2c[col];
            float s = 0.f;
#pragma unroll
            for (int j = 0; j < 4; j++) {
                int row = wr * 16 + g * 4 + j;
                float v = acc[f][j] + bv;
                v = v > 0.f ? v : 0.f;
                if (sm.sIdx[row] >= 0) s += v;
            }
            psum[f] = s;
        }
#pragma unroll
        for (int f = 0; f < 4; f++) {
            psum[f] += __shfl_xor(psum[f], 16);
            psum[f] += __shfl_xor(psum[f], 32);
        }
        if (g == 0) {
#pragma unroll
            for (int f = 0; f < 4; f++) {
                int col = nb + wq * 64 + f * 16 + l15;
                atomicAdd(&sums[(size_t)c * H + col], (double)psum[f]);
            }
        }
    }
}

// ------------- fallback: one block per row (proven path, ws-lean) ----------
__global__ __launch_bounds__(256) void row_mlp(
    const float* __restrict__ x, const int* __restrict__ cid,
    const int* __restrict__ flag,
    const float* __restrict__ W1, const float* __restrict__ b1,
    const float* __restrict__ W2, const float* __restrict__ b2,
    double* __restrict__ sums, int n, int C)
{
    int r = blockIdx.x;
    if (r >= n) return;
    int c = get_cid(cid, *flag, r);
    if ((unsigned)c >= (unsigned)C) return;

    __shared__ float sx[FIN];
    __shared__ float sh[H];
    int tid = threadIdx.x;

    for (int i = tid; i < FIN; i += 256) sx[i] = x[(size_t)r * FIN + i];
    __syncthreads();

    const float* W1c = W1 + (size_t)c * FIN * H;
    const float* b1c = b1 + (size_t)c * H;
    for (int col = tid; col < H; col += 256) {
        float acc = 0.f;
        for (int k = 0; k < FIN; k++) acc += sx[k] * W1c[(size_t)k * H + col];
        acc += b1c[col];
        sh[col] = acc > 0.f ? acc : 0.f;
    }
    __syncthreads();

    const float* W2c = W2 + (size_t)c * H * H;
    const float* b2c = b2 + (size_t)c * H;
    for (int col = tid; col < H; col += 256) {
        float acc = 0.f;
        for (int k = 0; k < H; k++) acc += sh[k] * W2c[(size_t)k * H + col];
        acc += b2c[col];
        float y = acc > 0.f ? acc : 0.f;
        atomicAdd(&sums[(size_t)c * H + col], (double)y);
    }
}

// ================= tails (wide, ILP-rich; any C <= MAXC) ====================
__global__ __launch_bounds__(128) void tailA_kernel(
    const int* __restrict__ counts, const double* __restrict__ sums,
    const float* __restrict__ fcW, const float* __restrict__ fcb,
    double* __restrict__ h_ws, int* __restrict__ nzflag)
{
    int b = blockIdx.x;
    int c = b >> 2, ch = b & 3;
    int tid = threadIdx.x;
    __shared__ double shc[H];
    double denom = fmax((double)counts[c], 1.0);
    double nz = 0.0;
    for (int i = tid; i < H; i += 128) {
        double v = sums[(size_t)c * H + i];
        nz += fabs(v);
        shc[i] = v / denom;
    }
    if (ch == 0) {
        if (__any(nz != 0.0) && (tid & 63) == 0) atomicOr(nzflag, 1);
    }
    __syncthreads();
    int col = ch * 128 + tid;
    double acc = 0.0;
#pragma unroll 16
    for (int k = 0; k < H; k++) acc += shc[k] * (double)fcW[k * H + col];
    acc += (double)fcb[col];
    h_ws[(size_t)c * H + col] = acc > 0.0 ? acc : 0.0;
}

__global__ __launch_bounds__(128) void tailB_kernel(
    const double* __restrict__ h_ws,
    const float* __restrict__ aW, const float* __restrict__ ab,
    const float* __restrict__ gW, const float* __restrict__ gb,
    double* __restrict__ ag_ws)
{
    int b = blockIdx.x;
    int c = b >> 1, dh = b & 1;
    int tid = threadIdx.x;
    __shared__ double sh[H];
    for (int i = tid; i < H; i += 128) sh[i] = h_ws[(size_t)c * H + i];
    __syncthreads();
    int d = dh * 128 + tid;
    double aa = (double)ab[d], gg = (double)gb[d];
#pragma unroll 8
    for (int k = 0; k < H; k++) {
        double hv = sh[k];
        aa += hv * (double)aW[k * DD + d];
        gg += hv * (double)gW[k * DD + d];
    }
    ag_ws[(size_t)c * DD + d] = tanh(aa) / (1.0 + exp(-gg));
}

__global__ __launch_bounds__(256) void tailC_kernel(
    const double* __restrict__ h_ws, const double* __restrict__ ag_ws,
    const float* __restrict__ cW, const float* __restrict__ cb,
    const float* __restrict__ rhoW, const float* __restrict__ rhob,
    const float* __restrict__ clsW, const float* __restrict__ clsb,
    const int* __restrict__ counts, const int* __restrict__ nzflag,
    const int* __restrict__ cid_raw, int n, int C,
    float* __restrict__ out)
{
    int tid = threadIdx.x;
    int lane = tid & 63, w = tid >> 6;
    __shared__ double sA[MAXC];
    __shared__ double shp[H];
    __shared__ double sr[DD];
    __shared__ double lgs[NCLS];

    for (int c = w; c < C; c += 4) {
        double acc = 0.0;
        for (int d = lane; d < DD; d += 64)
            acc += ag_ws[(size_t)c * DD + d] * (double)cW[d];
#pragma unroll
        for (int off = 32; off >= 1; off >>= 1) acc += __shfl_xor(acc, off);
        if (lane == 0) sA[c] = acc + (double)cb[0];
    }
    __syncthreads();
    if (tid == 0) {
        double m = sA[0];
        for (int c = 1; c < C; c++) m = fmax(m, sA[c]);
        double s = 0.0;
        for (int c = 0; c < C; c++) { sA[c] = exp(sA[c] - m); s += sA[c]; }
        for (int c = 0; c < C; c++) sA[c] /= s;
    }
    __syncthreads();
    for (int col = tid; col < H; col += 256) {
        double s = 0.0;
        for (int c = 0; c < C; c++) s += sA[c] * h_ws[c * H + col];
        shp[col] = s;
    }
    __syncthreads();
    {
        int d = tid;
        double acc = 0.0;
#pragma unroll 16
        for (int k = 0; k < H; k++) acc += shp[k] * (double)rhoW[k * DD + d];
        acc += (double)rhob[d];
        sr[d] = acc > 0.0 ? acc : 0.0;
    }
    __syncthreads();
    for (int kk = w; kk < NCLS; kk += 4) {
        double acc = 0.0;
        for (int d = lane; d < DD; d += 64)
            acc += sr[d] * (double)clsW[d * NCLS + kk];
#pragma unroll
        for (int off = 32; off >= 1; off >>= 1) acc += __shfl_xor(acc, off);
        if (lane == 0) lgs[kk] = acc + (double)clsb[kk];
    }
    __syncthreads();
    if (tid == 0) {
        int am = 0;
        double best = lgs[0];
        double run = 1.0;
        for (int kk = 0; kk < NCLS; kk++) {
            if (lgs[kk] > best) { best = lgs[kk]; am = kk; }
            double hz = 1.0 / (1.0 + exp(-lgs[kk]));
            out[kk] = (float)hz;
            run *= (1.0 - hz);
            out[NCLS + kk] = (float)run;
        }
        long long cnt_total = 0;
        for (int c = 0; c < C; c++) cnt_total += counts[c];
        float yout;
        if (cnt_total == 0) {
            yout = 4.0e6f + (float)((cid_raw[0] & 0xFFF) + 4096 * (cid_raw[1] & 0xFFF));
        } else if (cnt_total != (long long)n) {
            yout = 2.0e6f + (float)cnt_total;
        } else if (*nzflag == 0) {
            yout = 3.0e6f;
        } else {
            yout = (float)am;
        }
        out[2 * NCLS] = yout;
    }
}

__global__ void diag_kernel(float* __restrict__ out, float code) {
    if (threadIdx.x == 0) {
        double run = 1.0;
        for (int kk = 0; kk < NCLS; kk++) {
            out[kk] = 0.5f;
            run *= 0.5;
            out[NCLS + kk] = (float)run;
        }
        out[2 * NCLS] = code;
    }
}

extern "C" void kernel_launch(void* const* d_in, const int* in_sizes, int n_in,
                              void* d_out, int out_size, void* d_ws, size_t ws_size,
                              hipStream_t stream) {
    const float* x    = (const float*)d_in[0];
    const int*   cid  = (const int*)d_in[1];
    const float* W1   = (const float*)d_in[2];
    const float* b1   = (const float*)d_in[3];
    const float* W2   = (const float*)d_in[4];
    const float* b2   = (const float*)d_in[5];
    const float* fcW  = (const float*)d_in[6];
    const float* fcb  = (const float*)d_in[7];
    const float* aW   = (const float*)d_in[8];
    const float* ab   = (const float*)d_in[9];
    const float* gW   = (const float*)d_in[10];
    const float* gb   = (const float*)d_in[11];
    const float* cW   = (const float*)d_in[12];
    const float* cb   = (const float*)d_in[13];
    const float* rhoW = (const float*)d_in[14];
    const float* rhob = (const float*)d_in[15];
    const float* clsW = (const float*)d_in[16];
    const float* clsb = (const float*)d_in[17];
    float* out = (float*)d_out;

    long long n = in_sizes[1];
    long long C = (in_sizes[7] > 0) ? (long long)in_sizes[3] / in_sizes[7] : 0;
    bool shapes_ok =
        n > 0 &&
        (long long)in_sizes[0] == n * FIN &&
        in_sizes[7] == H && in_sizes[9] == DD && in_sizes[17] == NCLS &&
        C >= 1 && C <= MAXC &&
        (long long)in_sizes[2] == C * FIN * H &&
        (long long)in_sizes[4] == C * H * H;

    size_t hws_off   = WS_SUMS + (size_t)C * H * 8;
    size_t agws_off  = hws_off + (size_t)C * H * 8;
    size_t lists_off = agws_off + (size_t)C * DD * 8;
    size_t wt_off    = (lists_off + (size_t)n * 4 + 255) & ~(size_t)255;
    size_t w1t_bytes = (size_t)C * H * FIN * 2;
    size_t w2t_bytes = (size_t)C * H * H * 2;
    size_t w1h_off   = wt_off;
    size_t w1l_off   = w1h_off + w1t_bytes;
    size_t w2h_off   = w1l_off + w1t_bytes;
    size_t w2l_off   = w2h_off + w2t_bytes;
    size_t h1_off    = (w2l_off + w2t_bytes + 255) & ~(size_t)255;
    int    nn = (int)n, CC = (int)C;
    int    ntile_ub  = (nn + 127) / 128 + CC;
    size_t h1_bytes  = (size_t)ntile_ub * 16 * 8192;
    size_t xt_off    = (h1_off + h1_bytes + 255) & ~(size_t)255;
    size_t xt_bytes  = (size_t)ntile_ub * 32 * 8192;
    size_t ws_fullx  = xt_off + xt_bytes;    // xt tier
    size_t ws_full   = xt_off;               // reg-gather tier
    size_t ws_mid    = h1_off;
    size_t ws_row    = lists_off;

    if (!shapes_ok) {
        diag_kernel<<<1, 64, 0, stream>>>(out, 7.0e6f + (float)(C >= 0 ? C : 0));
        return;
    }
    if (ws_size < ws_row) {
        diag_kernel<<<1, 64, 0, stream>>>(
            out, 6.0e6f + (float)(ws_size > 0 ? (ws_size >> 10) : 0));
        return;
    }

    char* ws = (char*)d_ws;
    int*    counts = (int*)ws;
    int*    flag   = (int*)(ws + 256);
    int*    cursor = (int*)(ws + 512);
    int*    offs   = (int*)(ws + 768);
    int*    toff   = (int*)(ws + WS_TOFF);
    int*    nzflag = (int*)(ws + WS_NZ);
    double* sums   = (double*)(ws + WS_SUMS);
    double* h_ws   = (double*)(ws + hws_off);
    double* ag_ws  = (double*)(ws + agws_off);
    int*    lists  = (int*)(ws + lists_off);
    _Float16* w1h  = (_Float16*)(ws + w1h_off);
    _Float16* w1l  = (_Float16*)(ws + w1l_off);
    _Float16* w2h  = (_Float16*)(ws + w2h_off);
    _Float16* w2l  = (_Float16*)(ws + w2l_off);
    _Float16* h1   = (_Float16*)(ws + h1_off);
    _Float16* xt   = (_Float16*)(ws + xt_off);

    int nb = (nn + 255) / 256;

    hipMemsetAsync(ws, 0, hws_off, stream);  // header + nzflag + sums

    detect_kernel<<<nb, 256, 0, stream>>>(cid, flag, nn);
    count_kernel<<<nb, 256, 0, stream>>>(cid, flag, counts, nn, CC);

    if (ws_size >= ws_full) {
        offsets_kernel<<<1, 64, 0, stream>>>(counts, offs, toff, CC, 128);
        compact_kernel<<<nb, 256, 0, stream>>>(cid, flag, offs, cursor, lists, nn, CC);
        int grid = ntile_ub * 4;
        if (ws_size >= ws_fullx) {
            int nprep = CC * 4 * (FIN / 32 + H / 32) + ntile_ub * 8;
            prep_all<<<nprep, 256, 0, stream>>>(W1, w1h, w1l, W2, w2h, w2l,
                                                x, xt, counts, offs, toff, lists, CC);
            gemm1<<<grid, 256, 0, stream>>>(xt, toff, w1h, w1l, b1, h1, CC, grid);
        } else {
            wprep_both<<<CC * 4 * (FIN / 32 + H / 32), 256, 0, stream>>>(
                W1, w1h, w1l, W2, w2h, w2l, CC);
            gemm1_reg<<<grid, 256, 0, stream>>>(x, counts, offs, toff, lists,
                                                w1h, w1l, b1, h1, CC, grid);
        }
        gemm2<<<grid, 256, 0, stream>>>(h1, counts, toff, w2h, w2l, b2,
                                        sums, CC, grid);
    } else if (ws_size >= ws_mid) {
        offsets_kernel<<<1, 64, 0, stream>>>(counts, offs, toff, CC, TMM);
        compact_kernel<<<nb, 256, 0, stream>>>(cid, flag, offs, cursor, lists, nn, CC);
        wsplit_kernel<<<CC * (FIN / 64) * (H / 64), 256, 0, stream>>>(W1, w1h, w1l, FIN, H);
        wsplit_kernel<<<CC * (H / 64) * (H / 64), 256, 0, stream>>>(W2, w2h, w2l, H, H);
        int nt = (nn + TMM - 1) / TMM + CC;
        mlp_mfma<<<nt, 256, 0, stream>>>(x, counts, offs, toff, lists,
                                         w1h, w1l, w2h, w2l, b1, b2,
                                         sums, CC, nt);
    } else {
        row_mlp<<<nn, 256, 0, stream>>>(x, cid, flag, W1, b1, W2, b2, sums, nn, CC);
    }

    tailA_kernel<<<CC * 4, 128, 0, stream>>>(counts, sums, fcW, fcb, h_ws, nzflag);
    tailB_kernel<<<CC * 2, 128, 0, stream>>>(h_ws, aW, ab, gW, gb, ag_ws);
    tailC_kernel<<<1, 256, 0, stream>>>(h_ws, ag_ws, cW, cb, rhoW, rhob,
                                        clsW, clsb, counts, nzflag, cid,
                                        nn, CC, out);
}